// Round 2
// baseline (6234.016 us; speedup 1.0000x reference)
//
#include <hip/hip_runtime.h>
#include <math.h>

#define BB 128   // batch
#define SS 128   // seq len
#define EE 300   // embed dim
#define HH 256   // per-direction hidden
#define G4 1024  // 4*HH gate width
#define TT 16    // tagset
#define NEGV -10000.0f
#define START_TAG 14
#define STOP_TAG 15

__device__ __forceinline__ float sigm(float x) { return 1.0f / (1.0f + expf(-x)); }

__device__ __forceinline__ float4 shfl_xor4(float4 v, int m) {
  float4 r;
  r.x = __shfl_xor(v.x, m); r.y = __shfl_xor(v.y, m);
  r.z = __shfl_xor(v.z, m); r.w = __shfl_xor(v.w, m);
  return r;
}
__device__ __forceinline__ void add4(float4& a, const float4& b) {
  a.x += b.x; a.y += b.y; a.z += b.z; a.w += b.w;
}

// ---------------- prep: weight transposes + bias folding + ctr zero ----------------
// WihT[d][e][j] = Wih_d[j][e]           (2*300*1024)
// Whh4[d][k][u*4+g] = Whh_d[g*256+u][k] (2*256*1024)  -> float4 per (k,u)
// bsum[d][j] = bih_d[j] + bhh_d[j]      (2*1024)
__global__ void k_prep(const float* __restrict__ Wih_f, const float* __restrict__ Whh_f,
                       const float* __restrict__ bih_f, const float* __restrict__ bhh_f,
                       const float* __restrict__ Wih_b, const float* __restrict__ Whh_b,
                       const float* __restrict__ bih_b, const float* __restrict__ bhh_b,
                       float* __restrict__ WihT, float* __restrict__ Whh4,
                       float* __restrict__ bsum, int* __restrict__ ctr) {
  int id = blockIdx.x * blockDim.x + threadIdx.x;
  const int N1 = 2 * EE * G4;
  const int N2 = 2 * HH * G4;
  const int N3 = 2 * G4;
  if (id < N1) {
    int d = id / (EE * G4); int r = id % (EE * G4);
    int e = r / G4; int j = r % G4;
    const float* W = d ? Wih_b : Wih_f;
    WihT[id] = W[j * EE + e];
  } else if (id < N1 + N2) {
    int t = id - N1;
    int d = t / (HH * G4); int r = t % (HH * G4);
    int k = r / G4; int q = r % G4; int u = q >> 2; int g = q & 3;
    const float* W = d ? Whh_b : Whh_f;
    Whh4[t] = W[(g * HH + u) * HH + k];
  } else if (id < N1 + N2 + N3) {
    int t = id - N1 - N2;
    int d = t / G4; int j = t % G4;
    bsum[t] = d ? (bih_b[j] + bhh_b[j]) : (bih_f[j] + bhh_f[j]);
  } else if (id < N1 + N2 + N3 + 32) {
    ctr[(id - N1 - N2 - N3) * 64] = 0;
  }
}

// ---------------- input projection GEMM (gathered) ----------------
// xp4[d][s][b][u] = float4(i,f,g,o) = bsum + sum_e emb[sent[b][s]][e] * Wih_d[:,e]
__global__ void k_xproj(const int* __restrict__ sent, const float* __restrict__ emb,
                        const float* __restrict__ WihT, const float* __restrict__ bsum,
                        float4* __restrict__ xp4) {
  __shared__ float xs[16][EE];
  __shared__ int idxs[16];
  int blk = blockIdx.x;
  int d = blk >> 10;
  int tile = blk & 1023;
  int tid = threadIdx.x;
  if (tid < 16) {
    int sb = tile * 16 + tid;
    int s = sb >> 7, b = sb & 127;
    idxs[tid] = sent[b * SS + s];
  }
  __syncthreads();
  for (int t = tid; t < 16 * EE; t += 256) {
    int i = t / EE, e = t % EE;
    xs[i][e] = emb[(size_t)idxs[i] * EE + e];
  }
  __syncthreads();

  const float* WT = WihT + (size_t)d * EE * G4;
  float acc0[16], acc1[16], acc2[16], acc3[16];
#pragma unroll
  for (int i = 0; i < 16; ++i) { acc0[i] = 0.f; acc1[i] = 0.f; acc2[i] = 0.f; acc3[i] = 0.f; }

  for (int e = 0; e < EE; ++e) {
    const float* row = WT + (size_t)e * G4;
    float w0 = row[tid];
    float w1 = row[tid + 256];
    float w2 = row[tid + 512];
    float w3 = row[tid + 768];
#pragma unroll
    for (int i = 0; i < 16; ++i) {
      float x = xs[i][e];
      acc0[i] += w0 * x; acc1[i] += w1 * x; acc2[i] += w2 * x; acc3[i] += w3 * x;
    }
  }
  float b0 = bsum[d * G4 + tid];
  float b1 = bsum[d * G4 + tid + 256];
  float b2 = bsum[d * G4 + tid + 512];
  float b3 = bsum[d * G4 + tid + 768];
#pragma unroll
  for (int i = 0; i < 16; ++i) {
    int sb = tile * 16 + i;
    int s = sb >> 7, b = sb & 127;
    xp4[(((size_t)d * SS + s) * BB + b) * HH + tid] =
        make_float4(acc0[i] + b0, acc1[i] + b1, acc2[i] + b2, acc3[i] + b3);
  }
}

// ---------------- recurrent LSTM: weights in VGPRs, 8-block group barrier ----------------
// grid 256 (cooperative): blk = d*128 + bg*8 + sl. 256 thr: tid = u*8 + kc.
// Each thread holds Whh[u-slice][k-chunk] (32 float4) in registers.
__global__ __launch_bounds__(256, 1) void k_recur(
    const float4* __restrict__ xp4, const float4* __restrict__ Wg,
    const float* __restrict__ Wout, const float* __restrict__ h0,
    const float* __restrict__ c0, float* __restrict__ hbuf,
    float* __restrict__ featsP, int* __restrict__ ctr) {
  __shared__ float hshS[8 * 288];   // h staging, kc-swizzled (stride 36 per 32-chunk)
  __shared__ float hloc[8 * 33];    // this step's h for feats (padded)
  __shared__ float WoL[16 * 33];    // Wout slice (padded)

  int blk = blockIdx.x;
  int d = blk >> 7;
  int bg = (blk >> 3) & 15;
  int sl = blk & 7;
  int bbase = bg * 8;
  int tid = threadIdx.x;
  int u = tid >> 3, kc = tid & 7;
  int uglob = sl * 32 + u;
  int* ctrg = ctr + (d * 16 + bg) * 64;

  for (int i = tid; i < 16 * 32; i += 256) {
    int t = i >> 5, uu = i & 31;
    WoL[t * 33 + uu] = Wout[t * 512 + d * HH + sl * 32 + uu];
  }

  // Whh slice -> registers: wreg[kk] = Whh4[d][kc*32+kk][uglob] (i,f,g,o)
  float4 wreg[32];
  {
    const float4* Wd = Wg + (size_t)d * (HH * HH) + (size_t)(kc * 32) * HH + uglob;
#pragma unroll
    for (int kk = 0; kk < 32; ++kk) wreg[kk] = Wd[(size_t)kk * HH];
  }
  int b_own = ((kc & 1) << 2) | (kc & 2) | ((kc >> 2) & 1);
  float c_reg = c0[((size_t)d * BB + bbase + b_own) * HH + uglob];
  bool up0 = (kc & 1), up1 = (kc & 2), up2 = (kc & 4);

  for (int step = 0; step < SS; ++step) {
    int s = d ? (SS - 1 - step) : step;
    // stage previous h (8 batches x 256) into swizzled LDS
    const float* hsrc = (step == 0)
        ? (h0 + ((size_t)d * BB + bbase) * HH)
        : (hbuf + ((size_t)((step - 1) % 3) * 2 + d) * BB * HH + (size_t)bbase * HH);
    for (int i = tid; i < 2048; i += 256) {
      int b = i >> 8, k = i & 255;
      hshS[b * 288 + (k >> 5) * 36 + (k & 31)] = hsrc[i];
    }
    __syncthreads();

    // gate partials: a[b] = sum over this thread's 32-k chunk
    float4 a[8];
#pragma unroll
    for (int b = 0; b < 8; ++b) a[b] = make_float4(0.f, 0.f, 0.f, 0.f);

#pragma unroll
    for (int kk4 = 0; kk4 < 8; ++kk4) {
      float hvv[8][4];
#pragma unroll
      for (int b = 0; b < 8; ++b)
        *(float4*)&hvv[b][0] = *(const float4*)&hshS[b * 288 + kc * 36 + kk4 * 4];
#pragma unroll
      for (int j = 0; j < 4; ++j) {
        float4 w = wreg[kk4 * 4 + j];
#pragma unroll
        for (int b = 0; b < 8; ++b) {
          float hj = hvv[b][j];
          a[b].x += w.x * hj; a[b].y += w.y * hj;
          a[b].z += w.z * hj; a[b].w += w.w * hj;
        }
      }
    }

    // reduce-scatter over kc (8 lanes) -> thread owns batch b_own, static reg indices
#pragma unroll
    for (int j = 0; j < 4; ++j) {
      float4 snd = up0 ? a[j] : a[j + 4];
      float4 rcv = shfl_xor4(snd, 1);
      if (!up0) add4(a[j], rcv); else add4(a[j + 4], rcv);
    }
    float4 v0 = up0 ? a[4] : a[0];
    float4 v1 = up0 ? a[5] : a[1];
    float4 v2 = up0 ? a[6] : a[2];
    float4 v3 = up0 ? a[7] : a[3];
    {
      float4 snd = up1 ? v0 : v2;
      float4 rcv = shfl_xor4(snd, 2);
      if (!up1) add4(v0, rcv); else add4(v2, rcv);
      snd = up1 ? v1 : v3;
      rcv = shfl_xor4(snd, 2);
      if (!up1) add4(v1, rcv); else add4(v3, rcv);
    }
    float4 w0 = up1 ? v2 : v0;
    float4 w1 = up1 ? v3 : v1;
    {
      float4 snd = up2 ? w0 : w1;
      float4 rcv = shfl_xor4(snd, 4);
      if (!up2) add4(w0, rcv); else add4(w1, rcv);
    }
    float4 g4 = up2 ? w1 : w0;

    // + input projection, nonlinearity
    float4 xg = xp4[(((size_t)d * SS + s) * BB + bbase + b_own) * HH + uglob];
    float ii = g4.x + xg.x, ff = g4.y + xg.y, gg = g4.z + xg.z, oo = g4.w + xg.w;
    c_reg = sigm(ff) * c_reg + sigm(ii) * tanhf(gg);
    float hn = sigm(oo) * tanhf(c_reg);

    hloc[b_own * 33 + u] = hn;
    hbuf[((size_t)(step % 3) * 2 + d) * BB * HH + (size_t)(bbase + b_own) * HH + uglob] = hn;
    __threadfence();
    __syncthreads();

    // feats slice contribution: 256 thr = (b2, t, pr)
    {
      int b2 = tid >> 5, t = (tid >> 1) & 15, pr = tid & 1;
      float p = 0.f;
#pragma unroll
      for (int q = 0; q < 16; ++q)
        p += hloc[b2 * 33 + pr * 16 + q] * WoL[t * 33 + pr * 16 + q];
      p += __shfl_xor(p, 1);
      if (!pr)
        featsP[(((size_t)(d * 8 + sl) * BB + bbase + b2) * SS + s) * TT + t] = p;
    }

    // 8-block group barrier
    if (tid == 0) {
      atomicAdd(ctrg, 1);
      while (__hip_atomic_load(ctrg, __ATOMIC_ACQUIRE, __HIP_MEMORY_SCOPE_AGENT) <
             8 * (step + 1))
        __builtin_amdgcn_s_sleep(1);
    }
    __syncthreads();
    __threadfence();
  }
}

// ---------------- feats slice reduction ----------------
// featsF[b][s][t] = sum_{dsl<16} featsP[dsl][b][s][t]
__global__ void k_fsum(const float* __restrict__ featsP, float* __restrict__ featsF) {
  int b = blockIdx.x;
  int tid = threadIdx.x;
  float acc[8];
#pragma unroll
  for (int j = 0; j < 8; ++j) acc[j] = 0.f;
  for (int dsl = 0; dsl < 16; ++dsl) {
    const float* fp = featsP + ((size_t)dsl * BB + b) * (SS * TT);
#pragma unroll
    for (int j = 0; j < 8; ++j) acc[j] += fp[j * 256 + tid];
  }
  float* fo = featsF + (size_t)b * (SS * TT);
#pragma unroll
  for (int j = 0; j < 8; ++j) fo[j * 256 + tid] = acc[j];
}

// ---------------- Viterbi ----------------
__global__ void k_viterbi(const float* __restrict__ featsF, const float* __restrict__ b_out,
                          const float* __restrict__ trans, float* __restrict__ out,
                          unsigned char* __restrict__ bp) {
  __shared__ float tr[TT * TT];
  int tid = threadIdx.x;
  if (tid < TT * TT) tr[tid] = trans[tid];
  __syncthreads();

  int bg = tid >> 4;
  int next = tid & 15;
  int b = blockIdx.x * 16 + bg;
  float fv = (next == START_TAG) ? 0.0f : NEGV;
  float bo = b_out[next];
  const float* fF = featsF + (size_t)b * SS * TT;

  for (int s = 0; s < SS; ++s) {
    float best = -INFINITY; int arg = 0;
#pragma unroll
    for (int prev = 0; prev < TT; ++prev) {
      float fvp = __shfl(fv, prev, 16);
      float cand = fvp + tr[next * TT + prev];
      if (cand > best) { best = cand; arg = prev; }
    }
    float feat = fF[s * TT + next] + bo;
    fv = best + feat;
    bp[((size_t)b * SS + s) * TT + next] = (unsigned char)arg;
  }

  float bv = fv + tr[STOP_TAG * TT + next];
  int bi = next;
#pragma unroll
  for (int off = 8; off; off >>= 1) {
    float ov = __shfl_down(bv, off, 16);
    int oi = __shfl_down(bi, off, 16);
    if (ov > bv || (ov == bv && oi < bi)) { bv = ov; bi = oi; }
  }
  if (next == 0) {
    out[b] = bv;
    int tag = bi;
    float* po = out + BB + (size_t)b * SS;
    for (int s = SS - 1; s >= 0; --s) {
      po[s] = (float)tag;
      tag = bp[((size_t)b * SS + s) * TT + tag];
    }
  }
}

// ---------------- host ----------------
extern "C" void kernel_launch(void* const* d_in, const int* in_sizes, int n_in,
                              void* d_out, int out_size, void* d_ws, size_t ws_size,
                              hipStream_t stream) {
  const int*   sent  = (const int*)d_in[0];
  const float* emb   = (const float*)d_in[1];
  const float* Wih_f = (const float*)d_in[2];
  const float* Whh_f = (const float*)d_in[3];
  const float* bih_f = (const float*)d_in[4];
  const float* bhh_f = (const float*)d_in[5];
  const float* Wih_b = (const float*)d_in[6];
  const float* Whh_b = (const float*)d_in[7];
  const float* bih_b = (const float*)d_in[8];
  const float* bhh_b = (const float*)d_in[9];
  const float* Wout  = (const float*)d_in[10];
  const float* b_out = (const float*)d_in[11];
  const float* trans = (const float*)d_in[12];
  const float* h0    = (const float*)d_in[13];
  const float* c0    = (const float*)d_in[14];

  float* ws = (float*)d_ws;
  size_t off = 0;
  float* xproj  = ws + off; off += (size_t)2 * SS * BB * G4;        // 33,554,432 fl
  float* WihT   = ws + off; off += (size_t)2 * EE * G4;             //    614,400
  float* Whh4   = ws + off; off += (size_t)2 * HH * G4;             //    524,288
  float* bsum   = ws + off; off += (size_t)2 * G4;                  //      2,048
  float* featsP = ws + off; off += (size_t)16 * BB * SS * TT;       //  4,194,304
  float* featsF = ws + off; off += (size_t)BB * SS * TT;            //    262,144
  float* hbuf   = ws + off; off += (size_t)3 * 2 * BB * HH;         //    196,608
  int*   ctr    = (int*)(ws + off); off += 2048;                    //      8 KB
  unsigned char* bp = (unsigned char*)(ws + off);                   //    262,144 B

  const int NPREP = 2 * EE * G4 + 2 * HH * G4 + 2 * G4 + 32;
  k_prep<<<(NPREP + 255) / 256, 256, 0, stream>>>(Wih_f, Whh_f, bih_f, bhh_f,
                                                  Wih_b, Whh_b, bih_b, bhh_b,
                                                  WihT, Whh4, bsum, ctr);
  k_xproj<<<2048, 256, 0, stream>>>(sent, emb, WihT, bsum, (float4*)xproj);

  {
    const float4* xp4c = (const float4*)xproj;
    const float4* Wgc  = (const float4*)Whh4;
    void* kargs[] = {(void*)&xp4c, (void*)&Wgc, (void*)&Wout, (void*)&h0,
                     (void*)&c0, (void*)&hbuf, (void*)&featsP, (void*)&ctr};
    hipError_t e = hipLaunchCooperativeKernel(k_recur, dim3(256), dim3(256),
                                              kargs, 0, stream);
    if (e != hipSuccess) {
      // fallback: plain launch (grid exactly fills device at 1 block/CU)
      k_recur<<<256, 256, 0, stream>>>(xp4c, Wgc, Wout, h0, c0, hbuf, featsP, ctr);
    }
  }

  k_fsum<<<BB, 256, 0, stream>>>(featsP, featsF);
  k_viterbi<<<8, 256, 0, stream>>>(featsF, b_out, trans, (float*)d_out, bp);
}

// Round 3
// 1097.903 us; speedup vs baseline: 5.6781x; 5.6781x over previous
//
#include <hip/hip_runtime.h>
#include <math.h>

#define BB 128   // batch
#define SS 128   // seq len
#define EE 300   // embed dim
#define HH 256   // per-direction hidden
#define G4 1024  // 4*HH gate width
#define TT 16    // tagset
#define NEGV -10000.0f
#define START_TAG 14
#define STOP_TAG 15

__device__ __forceinline__ float sigm(float x) { return 1.0f / (1.0f + expf(-x)); }

__device__ __forceinline__ float4 shfl_xor4(float4 v, int m) {
  float4 r;
  r.x = __shfl_xor(v.x, m); r.y = __shfl_xor(v.y, m);
  r.z = __shfl_xor(v.z, m); r.w = __shfl_xor(v.w, m);
  return r;
}
__device__ __forceinline__ void add4(float4& a, const float4& b) {
  a.x += b.x; a.y += b.y; a.z += b.z; a.w += b.w;
}

// ---------------- prep: weight transposes + bias folding + ctr zero ----------------
__global__ void k_prep(const float* __restrict__ Wih_f, const float* __restrict__ Whh_f,
                       const float* __restrict__ bih_f, const float* __restrict__ bhh_f,
                       const float* __restrict__ Wih_b, const float* __restrict__ Whh_b,
                       const float* __restrict__ bih_b, const float* __restrict__ bhh_b,
                       float* __restrict__ WihT, float* __restrict__ Whh4,
                       float* __restrict__ bsum, int* __restrict__ ctr) {
  int id = blockIdx.x * blockDim.x + threadIdx.x;
  const int N1 = 2 * EE * G4;
  const int N2 = 2 * HH * G4;
  const int N3 = 2 * G4;
  if (id < N1) {
    int d = id / (EE * G4); int r = id % (EE * G4);
    int e = r / G4; int j = r % G4;
    const float* W = d ? Wih_b : Wih_f;
    WihT[id] = W[j * EE + e];
  } else if (id < N1 + N2) {
    int t = id - N1;
    int d = t / (HH * G4); int r = t % (HH * G4);
    int k = r / G4; int q = r % G4; int u = q >> 2; int g = q & 3;
    const float* W = d ? Whh_b : Whh_f;
    Whh4[t] = W[(g * HH + u) * HH + k];
  } else if (id < N1 + N2 + N3) {
    int t = id - N1 - N2;
    int d = t / G4; int j = t % G4;
    bsum[t] = d ? (bih_b[j] + bhh_b[j]) : (bih_f[j] + bhh_f[j]);
  } else if (id < N1 + N2 + N3 + 32) {
    ctr[(id - N1 - N2 - N3) * 64] = 0;
  }
}

// ---------------- input projection GEMM (gathered) ----------------
__global__ void k_xproj(const int* __restrict__ sent, const float* __restrict__ emb,
                        const float* __restrict__ WihT, const float* __restrict__ bsum,
                        float4* __restrict__ xp4) {
  __shared__ float xs[16][EE];
  __shared__ int idxs[16];
  int blk = blockIdx.x;
  int d = blk >> 10;
  int tile = blk & 1023;
  int tid = threadIdx.x;
  if (tid < 16) {
    int sb = tile * 16 + tid;
    int s = sb >> 7, b = sb & 127;
    idxs[tid] = sent[b * SS + s];
  }
  __syncthreads();
  for (int t = tid; t < 16 * EE; t += 256) {
    int i = t / EE, e = t % EE;
    xs[i][e] = emb[(size_t)idxs[i] * EE + e];
  }
  __syncthreads();

  const float* WT = WihT + (size_t)d * EE * G4;
  float acc0[16], acc1[16], acc2[16], acc3[16];
#pragma unroll
  for (int i = 0; i < 16; ++i) { acc0[i] = 0.f; acc1[i] = 0.f; acc2[i] = 0.f; acc3[i] = 0.f; }

  for (int e = 0; e < EE; ++e) {
    const float* row = WT + (size_t)e * G4;
    float w0 = row[tid];
    float w1 = row[tid + 256];
    float w2 = row[tid + 512];
    float w3 = row[tid + 768];
#pragma unroll
    for (int i = 0; i < 16; ++i) {
      float x = xs[i][e];
      acc0[i] += w0 * x; acc1[i] += w1 * x; acc2[i] += w2 * x; acc3[i] += w3 * x;
    }
  }
  float b0 = bsum[d * G4 + tid];
  float b1 = bsum[d * G4 + tid + 256];
  float b2 = bsum[d * G4 + tid + 512];
  float b3 = bsum[d * G4 + tid + 768];
#pragma unroll
  for (int i = 0; i < 16; ++i) {
    int sb = tile * 16 + i;
    int s = sb >> 7, b = sb & 127;
    xp4[(((size_t)d * SS + s) * BB + b) * HH + tid] =
        make_float4(acc0[i] + b0, acc1[i] + b1, acc2[i] + b2, acc3[i] + b3);
  }
}

// ---------------- recurrent LSTM: weights in VGPRs, relaxed-atomic group barrier ----------------
// grid 256: blk = d*128 + bg*8 + sl. 256 thr: tid = u*8 + kc.
// All cross-block traffic via RELAXED agent-scope atomics (sc0/sc1 path, no
// buffer_wbl2/buffer_inv cache maintenance). Ordering: __syncthreads drains
// vmcnt(0) per wave, so h-stores are at the coherent point before tid0 posts ctr.
__global__ __launch_bounds__(256, 1) void k_recur(
    const float4* __restrict__ xp4, const float4* __restrict__ Wg,
    const float* __restrict__ Wout, const float* __restrict__ h0,
    const float* __restrict__ c0, float* __restrict__ hbuf,
    float* __restrict__ featsP, int* __restrict__ ctr) {
  __shared__ float hshS[8 * 288];   // h staging, kc-swizzled (stride 36 per 32-chunk)
  __shared__ float hloc[8 * 33];    // this step's h for feats (padded)
  __shared__ float WoL[16 * 33];    // Wout slice (padded)

  int blk = blockIdx.x;
  int d = blk >> 7;
  int bg = (blk >> 3) & 15;
  int sl = blk & 7;
  int bbase = bg * 8;
  int tid = threadIdx.x;
  int u = tid >> 3, kc = tid & 7;
  int uglob = sl * 32 + u;
  int* ctrg = ctr + (d * 16 + bg) * 64;

  for (int i = tid; i < 16 * 32; i += 256) {
    int t = i >> 5, uu = i & 31;
    WoL[t * 33 + uu] = Wout[t * 512 + d * HH + sl * 32 + uu];
  }

  // Whh slice -> registers: wreg[kk] = Whh4[d][kc*32+kk][uglob] (i,f,g,o)
  float4 wreg[32];
  {
    const float4* Wd = Wg + (size_t)d * (HH * HH) + (size_t)(kc * 32) * HH + uglob;
#pragma unroll
    for (int kk = 0; kk < 32; ++kk) wreg[kk] = Wd[(size_t)kk * HH];
  }
  int b_own = ((kc & 1) << 2) | (kc & 2) | ((kc >> 2) & 1);
  float c_reg = c0[((size_t)d * BB + bbase + b_own) * HH + uglob];
  bool up0 = (kc & 1), up1 = (kc & 2), up2 = (kc & 4);

  for (int step = 0; step < SS; ++step) {
    int s = d ? (SS - 1 - step) : step;
    // prefetch gate-input vec (independent of h) so it's in flight during the wait
    float4 xg = xp4[(((size_t)d * SS + s) * BB + bbase + b_own) * HH + uglob];

    // wait for previous step's h from all 8 slices (relaxed spin, no cache inv)
    if (step > 0) {
      if (tid == 0) {
        while (__hip_atomic_load(ctrg, __ATOMIC_RELAXED, __HIP_MEMORY_SCOPE_AGENT) <
               8 * step)
          __builtin_amdgcn_s_sleep(1);
      }
      __syncthreads();
    }

    // stage previous h (8 batches x 256) into swizzled LDS
    if (step == 0) {
      const float* hsrc = h0 + ((size_t)d * BB + bbase) * HH;
      for (int i = tid; i < 2048; i += 256) {
        int b = i >> 8, k = i & 255;
        hshS[b * 288 + (k >> 5) * 36 + (k & 31)] = hsrc[i];
      }
    } else {
      float* hsrc = hbuf + ((size_t)((step - 1) % 3) * 2 + d) * BB * HH + (size_t)bbase * HH;
      for (int i = tid; i < 2048; i += 256) {
        int b = i >> 8, k = i & 255;
        hshS[b * 288 + (k >> 5) * 36 + (k & 31)] =
            __hip_atomic_load(&hsrc[i], __ATOMIC_RELAXED, __HIP_MEMORY_SCOPE_AGENT);
      }
    }
    __syncthreads();

    // gate partials: a[b] = sum over this thread's 32-k chunk
    float4 a[8];
#pragma unroll
    for (int b = 0; b < 8; ++b) a[b] = make_float4(0.f, 0.f, 0.f, 0.f);

#pragma unroll
    for (int kk4 = 0; kk4 < 8; ++kk4) {
      float hvv[8][4];
#pragma unroll
      for (int b = 0; b < 8; ++b)
        *(float4*)&hvv[b][0] = *(const float4*)&hshS[b * 288 + kc * 36 + kk4 * 4];
#pragma unroll
      for (int j = 0; j < 4; ++j) {
        float4 w = wreg[kk4 * 4 + j];
#pragma unroll
        for (int b = 0; b < 8; ++b) {
          float hj = hvv[b][j];
          a[b].x += w.x * hj; a[b].y += w.y * hj;
          a[b].z += w.z * hj; a[b].w += w.w * hj;
        }
      }
    }

    // reduce-scatter over kc (8 lanes) -> thread owns batch b_own, static reg indices
#pragma unroll
    for (int j = 0; j < 4; ++j) {
      float4 snd = up0 ? a[j] : a[j + 4];
      float4 rcv = shfl_xor4(snd, 1);
      if (!up0) add4(a[j], rcv); else add4(a[j + 4], rcv);
    }
    float4 v0 = up0 ? a[4] : a[0];
    float4 v1 = up0 ? a[5] : a[1];
    float4 v2 = up0 ? a[6] : a[2];
    float4 v3 = up0 ? a[7] : a[3];
    {
      float4 snd = up1 ? v0 : v2;
      float4 rcv = shfl_xor4(snd, 2);
      if (!up1) add4(v0, rcv); else add4(v2, rcv);
      snd = up1 ? v1 : v3;
      rcv = shfl_xor4(snd, 2);
      if (!up1) add4(v1, rcv); else add4(v3, rcv);
    }
    float4 w0 = up1 ? v2 : v0;
    float4 w1 = up1 ? v3 : v1;
    {
      float4 snd = up2 ? w0 : w1;
      float4 rcv = shfl_xor4(snd, 4);
      if (!up2) add4(w0, rcv); else add4(w1, rcv);
    }
    float4 g4 = up2 ? w1 : w0;

    // + input projection, nonlinearity
    float ii = g4.x + xg.x, ff = g4.y + xg.y, gg = g4.z + xg.z, oo = g4.w + xg.w;
    c_reg = sigm(ff) * c_reg + sigm(ii) * tanhf(gg);
    float hn = sigm(oo) * tanhf(c_reg);

    // publish h to coherent point (relaxed atomic store, no fence)
    __hip_atomic_store(
        &hbuf[((size_t)(step % 3) * 2 + d) * BB * HH + (size_t)(bbase + b_own) * HH + uglob],
        hn, __ATOMIC_RELAXED, __HIP_MEMORY_SCOPE_AGENT);
    hloc[b_own * 33 + u] = hn;
    __syncthreads();   // drains vmcnt(0) per wave -> all h stores complete

    // post the signal ASAP, then do feats work (overlaps other blocks' spin-exit)
    if (tid == 0)
      __hip_atomic_fetch_add(ctrg, 1, __ATOMIC_RELAXED, __HIP_MEMORY_SCOPE_AGENT);

    // feats slice contribution: 256 thr = (b2, t, pr)
    {
      int b2 = tid >> 5, t = (tid >> 1) & 15, pr = tid & 1;
      float p = 0.f;
#pragma unroll
      for (int q = 0; q < 16; ++q)
        p += hloc[b2 * 33 + pr * 16 + q] * WoL[t * 33 + pr * 16 + q];
      p += __shfl_xor(p, 1);
      if (!pr)
        featsP[(((size_t)(d * 8 + sl) * BB + bbase + b2) * SS + s) * TT + t] = p;
    }
  }
}

// ---------------- feats slice reduction ----------------
__global__ void k_fsum(const float* __restrict__ featsP, float* __restrict__ featsF) {
  int b = blockIdx.x;
  int tid = threadIdx.x;
  float acc[8];
#pragma unroll
  for (int j = 0; j < 8; ++j) acc[j] = 0.f;
  for (int dsl = 0; dsl < 16; ++dsl) {
    const float* fp = featsP + ((size_t)dsl * BB + b) * (SS * TT);
#pragma unroll
    for (int j = 0; j < 8; ++j) acc[j] += fp[j * 256 + tid];
  }
  float* fo = featsF + (size_t)b * (SS * TT);
#pragma unroll
  for (int j = 0; j < 8; ++j) fo[j * 256 + tid] = acc[j];
}

// ---------------- Viterbi ----------------
__global__ void k_viterbi(const float* __restrict__ featsF, const float* __restrict__ b_out,
                          const float* __restrict__ trans, float* __restrict__ out,
                          unsigned char* __restrict__ bp) {
  __shared__ float tr[TT * TT];
  int tid = threadIdx.x;
  if (tid < TT * TT) tr[tid] = trans[tid];
  __syncthreads();

  int bg = tid >> 4;
  int next = tid & 15;
  int b = blockIdx.x * 16 + bg;
  float fv = (next == START_TAG) ? 0.0f : NEGV;
  float bo = b_out[next];
  const float* fF = featsF + (size_t)b * SS * TT;

  for (int s = 0; s < SS; ++s) {
    float best = -INFINITY; int arg = 0;
#pragma unroll
    for (int prev = 0; prev < TT; ++prev) {
      float fvp = __shfl(fv, prev, 16);
      float cand = fvp + tr[next * TT + prev];
      if (cand > best) { best = cand; arg = prev; }
    }
    float feat = fF[s * TT + next] + bo;
    fv = best + feat;
    bp[((size_t)b * SS + s) * TT + next] = (unsigned char)arg;
  }

  float bv = fv + tr[STOP_TAG * TT + next];
  int bi = next;
#pragma unroll
  for (int off = 8; off; off >>= 1) {
    float ov = __shfl_down(bv, off, 16);
    int oi = __shfl_down(bi, off, 16);
    if (ov > bv || (ov == bv && oi < bi)) { bv = ov; bi = oi; }
  }
  if (next == 0) {
    out[b] = bv;
    int tag = bi;
    float* po = out + BB + (size_t)b * SS;
    for (int s = SS - 1; s >= 0; --s) {
      po[s] = (float)tag;
      tag = bp[((size_t)b * SS + s) * TT + tag];
    }
  }
}

// ---------------- host ----------------
extern "C" void kernel_launch(void* const* d_in, const int* in_sizes, int n_in,
                              void* d_out, int out_size, void* d_ws, size_t ws_size,
                              hipStream_t stream) {
  const int*   sent  = (const int*)d_in[0];
  const float* emb   = (const float*)d_in[1];
  const float* Wih_f = (const float*)d_in[2];
  const float* Whh_f = (const float*)d_in[3];
  const float* bih_f = (const float*)d_in[4];
  const float* bhh_f = (const float*)d_in[5];
  const float* Wih_b = (const float*)d_in[6];
  const float* Whh_b = (const float*)d_in[7];
  const float* bih_b = (const float*)d_in[8];
  const float* bhh_b = (const float*)d_in[9];
  const float* Wout  = (const float*)d_in[10];
  const float* b_out = (const float*)d_in[11];
  const float* trans = (const float*)d_in[12];
  const float* h0    = (const float*)d_in[13];
  const float* c0    = (const float*)d_in[14];

  float* ws = (float*)d_ws;
  size_t off = 0;
  float* xproj  = ws + off; off += (size_t)2 * SS * BB * G4;        // 33,554,432 fl
  float* WihT   = ws + off; off += (size_t)2 * EE * G4;             //    614,400
  float* Whh4   = ws + off; off += (size_t)2 * HH * G4;             //    524,288
  float* bsum   = ws + off; off += (size_t)2 * G4;                  //      2,048
  float* featsP = ws + off; off += (size_t)16 * BB * SS * TT;       //  4,194,304
  float* featsF = ws + off; off += (size_t)BB * SS * TT;            //    262,144
  float* hbuf   = ws + off; off += (size_t)3 * 2 * BB * HH;         //    196,608
  int*   ctr    = (int*)(ws + off); off += 2048;                    //      8 KB
  unsigned char* bp = (unsigned char*)(ws + off);                   //    262,144 B

  const int NPREP = 2 * EE * G4 + 2 * HH * G4 + 2 * G4 + 32;
  k_prep<<<(NPREP + 255) / 256, 256, 0, stream>>>(Wih_f, Whh_f, bih_f, bhh_f,
                                                  Wih_b, Whh_b, bih_b, bhh_b,
                                                  WihT, Whh4, bsum, ctr);
  k_xproj<<<2048, 256, 0, stream>>>(sent, emb, WihT, bsum, (float4*)xproj);

  {
    const float4* xp4c = (const float4*)xproj;
    const float4* Wgc  = (const float4*)Whh4;
    void* kargs[] = {(void*)&xp4c, (void*)&Wgc, (void*)&Wout, (void*)&h0,
                     (void*)&c0, (void*)&hbuf, (void*)&featsP, (void*)&ctr};
    hipError_t e = hipLaunchCooperativeKernel(k_recur, dim3(256), dim3(256),
                                              kargs, 0, stream);
    if (e != hipSuccess) {
      k_recur<<<256, 256, 0, stream>>>(xp4c, Wgc, Wout, h0, c0, hbuf, featsP, ctr);
    }
  }

  k_fsum<<<BB, 256, 0, stream>>>(featsP, featsF);
  k_viterbi<<<8, 256, 0, stream>>>(featsF, b_out, trans, (float*)d_out, bp);
}

// Round 5
// 855.989 us; speedup vs baseline: 7.2828x; 1.2826x over previous
//
#include <hip/hip_runtime.h>
#include <math.h>

#define BB 128   // batch
#define SS 128   // seq len
#define EE 300   // embed dim
#define HH 256   // per-direction hidden
#define G4 1024  // 4*HH gate width
#define TT 16    // tagset
#define NEGV -10000.0f
#define START_TAG 14
#define STOP_TAG 15

typedef float f32x4 __attribute__((ext_vector_type(4)));
typedef int   i32x4 __attribute__((ext_vector_type(4)));

__device__ __forceinline__ float sigm(float x) { return 1.0f / (1.0f + expf(-x)); }

__device__ __forceinline__ float4 shfl_xor4(float4 v, int m) {
  float4 r;
  r.x = __shfl_xor(v.x, m); r.y = __shfl_xor(v.y, m);
  r.z = __shfl_xor(v.z, m); r.w = __shfl_xor(v.w, m);
  return r;
}
__device__ __forceinline__ void add4(float4& a, const float4& b) {
  a.x += b.x; a.y += b.y; a.z += b.z; a.w += b.w;
}

// LLC-coherent vector loads: sc0 (bypass L1) + sc1 (bypass L2) -> read the
// device coherent point. Same strength as __hip_atomic_load(RELAXED, AGENT),
// which the R3 kernel already proved correct on this chip.
__device__ __forceinline__ void load_f8_llc(const float* p, f32x4& a, f32x4& b) {
  asm volatile("global_load_dwordx4 %0, %2, off sc0 sc1\n\t"
               "global_load_dwordx4 %1, %2, off offset:16 sc0 sc1\n\t"
               "s_waitcnt vmcnt(0)"
               : "=&v"(a), "=&v"(b) : "v"(p) : "memory");
}
__device__ __forceinline__ void load_tags8(const int* p, i32x4& a, i32x4& b) {
  asm volatile("global_load_dwordx4 %0, %2, off sc0 sc1\n\t"
               "global_load_dwordx4 %1, %2, off offset:16 sc0 sc1\n\t"
               "s_waitcnt vmcnt(0)"
               : "=&v"(a), "=&v"(b) : "v"(p) : "memory");
}

// ---------------- prep: weight transposes + bias folding + tag zero ----------------
__global__ void k_prep(const float* __restrict__ Wih_f, const float* __restrict__ Whh_f,
                       const float* __restrict__ bih_f, const float* __restrict__ bhh_f,
                       const float* __restrict__ Wih_b, const float* __restrict__ Whh_b,
                       const float* __restrict__ bih_b, const float* __restrict__ bhh_b,
                       float* __restrict__ WihT, float* __restrict__ Whh4,
                       float* __restrict__ bsum, int* __restrict__ ctr) {
  int id = blockIdx.x * blockDim.x + threadIdx.x;
  const int N1 = 2 * EE * G4;
  const int N2 = 2 * HH * G4;
  const int N3 = 2 * G4;
  if (id < N1) {
    int d = id / (EE * G4); int r = id % (EE * G4);
    int e = r / G4; int j = r % G4;
    const float* W = d ? Wih_b : Wih_f;
    WihT[id] = W[j * EE + e];
  } else if (id < N1 + N2) {
    int t = id - N1;
    int d = t / (HH * G4); int r = t % (HH * G4);
    int k = r / G4; int q = r % G4; int u = q >> 2; int g = q & 3;
    const float* W = d ? Whh_b : Whh_f;
    Whh4[t] = W[(g * HH + u) * HH + k];
  } else if (id < N1 + N2 + N3) {
    int t = id - N1 - N2;
    int d = t / G4; int j = t % G4;
    bsum[t] = d ? (bih_b[j] + bhh_b[j]) : (bih_f[j] + bhh_f[j]);
  } else if (id < N1 + N2 + N3 + 32 * 256) {
    ctr[id - N1 - N2 - N3] = 0;
  }
}

// ---------------- input projection GEMM (gathered) ----------------
__global__ void k_xproj(const int* __restrict__ sent, const float* __restrict__ emb,
                        const float* __restrict__ WihT, const float* __restrict__ bsum,
                        float4* __restrict__ xp4) {
  __shared__ float xs[16][EE];
  __shared__ int idxs[16];
  int blk = blockIdx.x;
  int d = blk >> 10;
  int tile = blk & 1023;
  int tid = threadIdx.x;
  if (tid < 16) {
    int sb = tile * 16 + tid;
    int s = sb >> 7, b = sb & 127;
    idxs[tid] = sent[b * SS + s];
  }
  __syncthreads();
  for (int t = tid; t < 16 * EE; t += 256) {
    int i = t / EE, e = t % EE;
    xs[i][e] = emb[(size_t)idxs[i] * EE + e];
  }
  __syncthreads();

  const float* WT = WihT + (size_t)d * EE * G4;
  float acc0[16], acc1[16], acc2[16], acc3[16];
#pragma unroll
  for (int i = 0; i < 16; ++i) { acc0[i] = 0.f; acc1[i] = 0.f; acc2[i] = 0.f; acc3[i] = 0.f; }

  for (int e = 0; e < EE; ++e) {
    const float* row = WT + (size_t)e * G4;
    float w0 = row[tid];
    float w1 = row[tid + 256];
    float w2 = row[tid + 512];
    float w3 = row[tid + 768];
#pragma unroll
    for (int i = 0; i < 16; ++i) {
      float x = xs[i][e];
      acc0[i] += w0 * x; acc1[i] += w1 * x; acc2[i] += w2 * x; acc3[i] += w3 * x;
    }
  }
  float b0 = bsum[d * G4 + tid];
  float b1 = bsum[d * G4 + tid + 256];
  float b2 = bsum[d * G4 + tid + 512];
  float b3 = bsum[d * G4 + tid + 768];
#pragma unroll
  for (int i = 0; i < 16; ++i) {
    int sb = tile * 16 + i;
    int s = sb >> 7, b = sb & 127;
    xp4[(((size_t)d * SS + s) * BB + b) * HH + tid] =
        make_float4(acc0[i] + b0, acc1[i] + b1, acc2[i] + b2, acc3[i] + b3);
  }
}

// ---------------- recurrent LSTM: weights in VGPRs, tag-word group sync ----------------
// grid 256: blk = d*128 + bg*8 + sl. 256 thr: tid = u*8 + kc.
// All cross-block traffic via the device coherent point (LLC): relaxed agent
// atomic stores for h/tags, sc0+sc1 vector loads for h/tags. Proven-safe class
// (R3). Sync = per-producer tag words, polled by ALL threads (no RMW, no
// barrier wake on the critical path).
__global__ __launch_bounds__(256, 1) void k_recur(
    const float4* __restrict__ xp4, const float4* __restrict__ Wg,
    const float* __restrict__ Wout, const float* __restrict__ h0,
    const float* __restrict__ c0, float* __restrict__ hbuf,
    float* __restrict__ featsP, int* __restrict__ ctr) {
  __shared__ __align__(16) float hshS[8 * 288];  // h staging, kc-swizzled
  __shared__ float hloc[8 * 33];                 // this step's h for feats
  __shared__ float WoL[16 * 33];                 // Wout slice

  int blk = blockIdx.x;
  int d = blk >> 7;
  int bg = (blk >> 3) & 15;
  int sl = blk & 7;
  int bbase = bg * 8;
  int tid = threadIdx.x;
  int u = tid >> 3, kc = tid & 7;
  int uglob = sl * 32 + u;
  // per-group 1KB region in ctr; tags at +64 words (own 128B line)
  int* tagsg = ctr + (d * 16 + bg) * 256 + 64;   // tags[sl] = last finished step + 1

  for (int i = tid; i < 16 * 32; i += 256) {
    int t = i >> 5, uu = i & 31;
    WoL[t * 33 + uu] = Wout[t * 512 + d * HH + sl * 32 + uu];
  }

  // Whh slice -> registers: wreg[kk] = Whh4[d][kc*32+kk][uglob] (i,f,g,o)
  float4 wreg[32];
  {
    const float4* Wd = Wg + (size_t)d * (HH * HH) + (size_t)(kc * 32) * HH + uglob;
#pragma unroll
    for (int kk = 0; kk < 32; ++kk) wreg[kk] = Wd[(size_t)kk * HH];
  }
  int b_own = ((kc & 1) << 2) | (kc & 2) | ((kc >> 2) & 1);
  float c_reg = c0[((size_t)d * BB + bbase + b_own) * HH + uglob];
  bool up0 = (kc & 1), up1 = (kc & 2), up2 = (kc & 4);

  // contiguous-8 staging: thread stages hsrc[tid*8 .. tid*8+7] into swizzled LDS
  float* ldst = hshS + (tid >> 5) * 288 + ((tid & 31) >> 2) * 36 + (tid & 3) * 8;

  for (int step = 0; step < SS; ++step) {
    int s = d ? (SS - 1 - step) : step;
    // prefetch gate-input vec (h-independent), in flight during the wait
    float4 xg = xp4[(((size_t)d * SS + s) * BB + bbase + b_own) * HH + uglob];

    if (step > 0) {
      // all threads poll the 8 tag words until every peer finished step-1
      i32x4 ta, tb;
      int m;
      do {
        load_tags8(tagsg, ta, tb);
        int m0 = min(min(ta[0], ta[1]), min(ta[2], ta[3]));
        int m1 = min(min(tb[0], tb[1]), min(tb[2], tb[3]));
        m = min(m0, m1);
      } while (m < step);
      const float* ps = hbuf + ((size_t)((step - 1) % 3) * 2 + d) * BB * HH +
                        (size_t)bbase * HH + (tid << 3);
      f32x4 a, b;
      load_f8_llc(ps, a, b);
      *(f32x4*)ldst = a;
      *(f32x4*)(ldst + 4) = b;
    } else {
      const float* ps = h0 + ((size_t)d * BB + bbase) * HH + (tid << 3);
      f32x4 a = *(const f32x4*)ps;
      f32x4 b = *(const f32x4*)(ps + 4);
      *(f32x4*)ldst = a;
      *(f32x4*)(ldst + 4) = b;
    }
    __syncthreads();

    // gate partials over this thread's 32-k chunk
    float4 a[8];
#pragma unroll
    for (int b = 0; b < 8; ++b) a[b] = make_float4(0.f, 0.f, 0.f, 0.f);
#pragma unroll
    for (int kk4 = 0; kk4 < 8; ++kk4) {
      float hvv[8][4];
#pragma unroll
      for (int b = 0; b < 8; ++b)
        *(float4*)&hvv[b][0] = *(const float4*)&hshS[b * 288 + kc * 36 + kk4 * 4];
#pragma unroll
      for (int j = 0; j < 4; ++j) {
        float4 w = wreg[kk4 * 4 + j];
#pragma unroll
        for (int b = 0; b < 8; ++b) {
          float hj = hvv[b][j];
          a[b].x += w.x * hj; a[b].y += w.y * hj;
          a[b].z += w.z * hj; a[b].w += w.w * hj;
        }
      }
    }

    // reduce-scatter over kc (static register indices)
#pragma unroll
    for (int j = 0; j < 4; ++j) {
      float4 snd = up0 ? a[j] : a[j + 4];
      float4 rcv = shfl_xor4(snd, 1);
      if (!up0) add4(a[j], rcv); else add4(a[j + 4], rcv);
    }
    float4 v0 = up0 ? a[4] : a[0];
    float4 v1 = up0 ? a[5] : a[1];
    float4 v2 = up0 ? a[6] : a[2];
    float4 v3 = up0 ? a[7] : a[3];
    {
      float4 snd = up1 ? v0 : v2;
      float4 rcv = shfl_xor4(snd, 2);
      if (!up1) add4(v0, rcv); else add4(v2, rcv);
      snd = up1 ? v1 : v3;
      rcv = shfl_xor4(snd, 2);
      if (!up1) add4(v1, rcv); else add4(v3, rcv);
    }
    float4 w0 = up1 ? v2 : v0;
    float4 w1 = up1 ? v3 : v1;
    {
      float4 snd = up2 ? w0 : w1;
      float4 rcv = shfl_xor4(snd, 4);
      if (!up2) add4(w0, rcv); else add4(w1, rcv);
    }
    float4 g4 = up2 ? w1 : w0;

    // + input projection, nonlinearity
    float ii = g4.x + xg.x, ff = g4.y + xg.y, gg = g4.z + xg.z, oo = g4.w + xg.w;
    c_reg = sigm(ff) * c_reg + sigm(ii) * tanhf(gg);
    float hn = sigm(oo) * tanhf(c_reg);

    // publish h to the coherent point (relaxed agent store)
    __hip_atomic_store(
        &hbuf[((size_t)(step % 3) * 2 + d) * BB * HH + (size_t)(bbase + b_own) * HH + uglob],
        hn, __ATOMIC_RELAXED, __HIP_MEMORY_SCOPE_AGENT);
    hloc[b_own * 33 + u] = hn;
    __syncthreads();   // drains vmcnt(0) per wave -> all h stores at LLC

    // fire-and-forget tag post (no RMW round trip)
    if (tid == 0)
      __hip_atomic_store(&tagsg[sl], step + 1, __ATOMIC_RELAXED,
                         __HIP_MEMORY_SCOPE_AGENT);

    // feats slice contribution: 256 thr = (b2, t, pr)
    {
      int b2 = tid >> 5, t = (tid >> 1) & 15, pr = tid & 1;
      float p = 0.f;
#pragma unroll
      for (int q = 0; q < 16; ++q)
        p += hloc[b2 * 33 + pr * 16 + q] * WoL[t * 33 + pr * 16 + q];
      p += __shfl_xor(p, 1);
      if (!pr)
        featsP[(((size_t)(d * 8 + sl) * BB + bbase + b2) * SS + s) * TT + t] = p;
    }
  }
}

// ---------------- feats slice reduction ----------------
__global__ void k_fsum(const float* __restrict__ featsP, float* __restrict__ featsF) {
  int b = blockIdx.x;
  int tid = threadIdx.x;
  float acc[8];
#pragma unroll
  for (int j = 0; j < 8; ++j) acc[j] = 0.f;
  for (int dsl = 0; dsl < 16; ++dsl) {
    const float* fp = featsP + ((size_t)dsl * BB + b) * (SS * TT);
#pragma unroll
    for (int j = 0; j < 8; ++j) acc[j] += fp[j * 256 + tid];
  }
  float* fo = featsF + (size_t)b * (SS * TT);
#pragma unroll
  for (int j = 0; j < 8; ++j) fo[j * 256 + tid] = acc[j];
}

// ---------------- Viterbi ----------------
__global__ void k_viterbi(const float* __restrict__ featsF, const float* __restrict__ b_out,
                          const float* __restrict__ trans, float* __restrict__ out,
                          unsigned char* __restrict__ bp) {
  __shared__ float tr[TT * TT];
  int tid = threadIdx.x;
  if (tid < TT * TT) tr[tid] = trans[tid];
  __syncthreads();

  int bg = tid >> 4;
  int next = tid & 15;
  int b = blockIdx.x * 16 + bg;
  float fv = (next == START_TAG) ? 0.0f : NEGV;
  float bo = b_out[next];
  const float* fF = featsF + (size_t)b * SS * TT;

  for (int s = 0; s < SS; ++s) {
    float best = -INFINITY; int arg = 0;
#pragma unroll
    for (int prev = 0; prev < TT; ++prev) {
      float fvp = __shfl(fv, prev, 16);
      float cand = fvp + tr[next * TT + prev];
      if (cand > best) { best = cand; arg = prev; }
    }
    float feat = fF[s * TT + next] + bo;
    fv = best + feat;
    bp[((size_t)b * SS + s) * TT + next] = (unsigned char)arg;
  }

  float bv = fv + tr[STOP_TAG * TT + next];
  int bi = next;
#pragma unroll
  for (int off = 8; off; off >>= 1) {
    float ov = __shfl_down(bv, off, 16);
    int oi = __shfl_down(bi, off, 16);
    if (ov > bv || (ov == bv && oi < bi)) { bv = ov; bi = oi; }
  }
  if (next == 0) {
    out[b] = bv;
    int tag = bi;
    float* po = out + BB + (size_t)b * SS;
    for (int s = SS - 1; s >= 0; --s) {
      po[s] = (float)tag;
      tag = bp[((size_t)b * SS + s) * TT + tag];
    }
  }
}

// ---------------- host ----------------
extern "C" void kernel_launch(void* const* d_in, const int* in_sizes, int n_in,
                              void* d_out, int out_size, void* d_ws, size_t ws_size,
                              hipStream_t stream) {
  const int*   sent  = (const int*)d_in[0];
  const float* emb   = (const float*)d_in[1];
  const float* Wih_f = (const float*)d_in[2];
  const float* Whh_f = (const float*)d_in[3];
  const float* bih_f = (const float*)d_in[4];
  const float* bhh_f = (const float*)d_in[5];
  const float* Wih_b = (const float*)d_in[6];
  const float* Whh_b = (const float*)d_in[7];
  const float* bih_b = (const float*)d_in[8];
  const float* bhh_b = (const float*)d_in[9];
  const float* Wout  = (const float*)d_in[10];
  const float* b_out = (const float*)d_in[11];
  const float* trans = (const float*)d_in[12];
  const float* h0    = (const float*)d_in[13];
  const float* c0    = (const float*)d_in[14];

  float* ws = (float*)d_ws;
  size_t off = 0;
  float* xproj  = ws + off; off += (size_t)2 * SS * BB * G4;        // 33,554,432 fl
  float* WihT   = ws + off; off += (size_t)2 * EE * G4;             //    614,400
  float* Whh4   = ws + off; off += (size_t)2 * HH * G4;             //    524,288
  float* bsum   = ws + off; off += (size_t)2 * G4;                  //      2,048
  float* featsP = ws + off; off += (size_t)16 * BB * SS * TT;       //  4,194,304
  float* featsF = ws + off; off += (size_t)BB * SS * TT;            //    262,144
  float* hbuf   = ws + off; off += (size_t)3 * 2 * BB * HH;         //    196,608
  int*   ctr    = (int*)(ws + off); off += 32 * 256;                //     32 KB
  unsigned char* bp = (unsigned char*)(ws + off);                   //    262,144 B

  const int NPREP = 2 * EE * G4 + 2 * HH * G4 + 2 * G4 + 32 * 256;
  k_prep<<<(NPREP + 255) / 256, 256, 0, stream>>>(Wih_f, Whh_f, bih_f, bhh_f,
                                                  Wih_b, Whh_b, bih_b, bhh_b,
                                                  WihT, Whh4, bsum, ctr);
  k_xproj<<<2048, 256, 0, stream>>>(sent, emb, WihT, bsum, (float4*)xproj);

  {
    const float4* xp4c = (const float4*)xproj;
    const float4* Wgc  = (const float4*)Whh4;
    void* kargs[] = {(void*)&xp4c, (void*)&Wgc, (void*)&Wout, (void*)&h0,
                     (void*)&c0, (void*)&hbuf, (void*)&featsP, (void*)&ctr};
    hipError_t e = hipLaunchCooperativeKernel(k_recur, dim3(256), dim3(256),
                                              kargs, 0, stream);
    if (e != hipSuccess) {
      k_recur<<<256, 256, 0, stream>>>(xp4c, Wgc, Wout, h0, c0, hbuf, featsP, ctr);
    }
  }

  k_fsum<<<BB, 256, 0, stream>>>(featsP, featsF);
  k_viterbi<<<8, 256, 0, stream>>>(featsF, b_out, trans, (float*)d_out, bp);
}